// Round 7
// baseline (182.722 us; speedup 1.0000x reference)
//
#include <hip/hip_runtime.h>
#include <hip/hip_bf16.h>

#define Bb 8
#define Cc 64
#define Tt 16
#define Hh 56
#define Ww 56
#define COUT 128
#define HW (Hh*Ww)            // 3136
#define THW (Tt*HW)           // 50176
#define NPG ((double)(32*THW))

typedef __attribute__((ext_vector_type(8))) short short8v;   // 8 bf16
typedef __attribute__((ext_vector_type(4))) float f32x4;

__device__ __forceinline__ unsigned short f2bf(float x) {
  __hip_bfloat16 h = __float2bfloat16(x);
  return *reinterpret_cast<unsigned short*>(&h);
}
__device__ __forceinline__ float blo(unsigned int u) {
  return __uint_as_float(u << 16);
}
__device__ __forceinline__ float bhi(unsigned int u) {
  return __uint_as_float(u & 0xFFFF0000u);
}
__device__ __forceinline__ unsigned int pack2(float a, float b) {
  return (unsigned int)f2bf(a) | ((unsigned int)f2bf(b) << 16);
}

// ---------------------------------------------------------------------------
// K1: fused depthwise spatial 3x3 + temporal 3-tap. One block per
// (b, channel-PAIR, t-quad). raw & ring planes live in LDS as packed bf16
// pairs. Block 0 also zeroes the stats buffer (runs before k2 in stream order).
// ---------------------------------------------------------------------------
__global__ __launch_bounds__(256) void k1_dwconv(
    const float* __restrict__ x,  const float* __restrict__ sw,
    const float* __restrict__ sb, const float* __restrict__ tw,
    const float* __restrict__ tb, unsigned int* __restrict__ zq,
    double* __restrict__ stats)
{
  __shared__ unsigned int raw[HW];        // 12.25 KB (bf16 pair)
  __shared__ unsigned int ring[3][HW];    // 36.75 KB

  const int tid = threadIdx.x;
  if (blockIdx.x == 0 && tid < 64) stats[tid] = 0.0;

  const int tq = blockIdx.x & 3;
  const int c2 = (blockIdx.x >> 2) & 31;
  const int b  =  blockIdx.x >> 7;
  const int t0 = tq * 4;
  const int ca = c2 * 2, cb = ca + 1;

  float s9a[9], s9b[9];
#pragma unroll
  for (int k = 0; k < 9; ++k) { s9a[k] = sw[ca * 9 + k]; s9b[k] = sw[cb * 9 + k]; }
  float ta3[3], tb3[3];
#pragma unroll
  for (int k = 0; k < 3; ++k) { ta3[k] = tw[ca * 3 + k]; tb3[k] = tw[cb * 3 + k]; }
  const float sba = sb[ca], sbb = sb[cb];
  const float tba = tb[ca], tbb = tb[cb];

  const float* xa = x + (size_t)(b * Cc + ca) * THW;
  const float* xb = x + (size_t)(b * Cc + cb) * THW;
  unsigned int* zbase = zq + (size_t)(b * 32 + c2) * THW;

  for (int tt = t0 - 1; tt <= t0 + 4; ++tt) {
    if (tt >= 0 && tt < Tt) {
      const float* xpa = xa + tt * HW;
      const float* xpb = xb + tt * HW;
      for (int f = tid; f < HW / 4; f += 256) {
        float4 va = *(const float4*)(xpa + f * 4);
        float4 vb = *(const float4*)(xpb + f * 4);
        uint4 pk;
        pk.x = pack2(va.x, vb.x);
        pk.y = pack2(va.y, vb.y);
        pk.z = pack2(va.z, vb.z);
        pk.w = pack2(va.w, vb.w);
        *(uint4*)&raw[f * 4] = pk;
      }
    }
    __syncthreads();

    if (tt >= 0 && tt < Tt) {
      unsigned int* rg = ring[tt % 3];
      for (int q = tid; q < HW / 4; q += 256) {
        int h  = q / 14;
        int w0 = (q - h * 14) * 4;
        float sa0 = sba, sa1 = sba, sa2 = sba, sa3 = sba;
        float sb0 = sbb, sb1 = sbb, sb2 = sbb, sb3 = sbb;
#pragma unroll
        for (int dh = -1; dh <= 1; ++dh) {
          int hh = h + dh;
          if (hh < 0 || hh > Hh - 1) continue;
          const unsigned int* rr = &raw[hh * Ww + w0];
          uint4 mv = *(const uint4*)rr;
          unsigned int lf = (w0 > 0)      ? rr[-1] : 0u;
          unsigned int rt = (w0 < Ww - 4) ? rr[4]  : 0u;
          float am1 = blo(lf),  a0 = blo(mv.x), a1 = blo(mv.y);
          float a2  = blo(mv.z), a3 = blo(mv.w), a4 = blo(rt);
          float bm1 = bhi(lf),  b0 = bhi(mv.x), b1 = bhi(mv.y);
          float b2  = bhi(mv.z), b3 = bhi(mv.w), b4 = bhi(rt);
          float k0a = s9a[(dh + 1) * 3 + 0], k1a = s9a[(dh + 1) * 3 + 1], k2a = s9a[(dh + 1) * 3 + 2];
          float k0b = s9b[(dh + 1) * 3 + 0], k1b = s9b[(dh + 1) * 3 + 1], k2b = s9b[(dh + 1) * 3 + 2];
          sa0 = fmaf(k0a, am1, fmaf(k1a, a0, fmaf(k2a, a1, sa0)));
          sa1 = fmaf(k0a, a0,  fmaf(k1a, a1, fmaf(k2a, a2, sa1)));
          sa2 = fmaf(k0a, a1,  fmaf(k1a, a2, fmaf(k2a, a3, sa2)));
          sa3 = fmaf(k0a, a2,  fmaf(k1a, a3, fmaf(k2a, a4, sa3)));
          sb0 = fmaf(k0b, bm1, fmaf(k1b, b0, fmaf(k2b, b1, sb0)));
          sb1 = fmaf(k0b, b0,  fmaf(k1b, b1, fmaf(k2b, b2, sb1)));
          sb2 = fmaf(k0b, b1,  fmaf(k1b, b2, fmaf(k2b, b3, sb2)));
          sb3 = fmaf(k0b, b2,  fmaf(k1b, b3, fmaf(k2b, b4, sb3)));
        }
        uint4 pk;
        pk.x = pack2(sa0, sb0);
        pk.y = pack2(sa1, sb1);
        pk.z = pack2(sa2, sb2);
        pk.w = pack2(sa3, sb3);
        *(uint4*)&rg[q * 4] = pk;
      }
    }
    __syncthreads();

    int t_out = tt - 1;
    if (t_out >= t0 && t_out <= t0 + 3) {
      unsigned int* zp = zbase + (size_t)t_out * HW;
      for (int q = tid; q < HW / 4; q += 256) {
        float aa0 = tba, aa1 = tba, aa2 = tba, aa3 = tba;
        float bb0 = tbb, bb1 = tbb, bb2 = tbb, bb3 = tbb;
#pragma unroll
        for (int dt = -1; dt <= 1; ++dt) {
          int ti = t_out + dt;
          if (ti < 0 || ti > Tt - 1) continue;
          float tka = ta3[dt + 1], tkb = tb3[dt + 1];
          uint4 v = *(const uint4*)&ring[ti % 3][q * 4];
          aa0 = fmaf(tka, blo(v.x), aa0);  bb0 = fmaf(tkb, bhi(v.x), bb0);
          aa1 = fmaf(tka, blo(v.y), aa1);  bb1 = fmaf(tkb, bhi(v.y), bb1);
          aa2 = fmaf(tka, blo(v.z), aa2);  bb2 = fmaf(tkb, bhi(v.z), bb2);
          aa3 = fmaf(tka, blo(v.w), aa3);  bb3 = fmaf(tkb, bhi(v.w), bb3);
        }
        uint4 o;
        o.x = pack2(aa0, bb0);
        o.y = pack2(aa1, bb1);
        o.z = pack2(aa2, bb2);
        o.w = pack2(aa3, bb3);
        *(uint4*)(zp + q * 4) = o;
      }
    }
    __syncthreads();
  }
}

// ---------------------------------------------------------------------------
// K2/K3: 128 pos x 128 out tile, 4 waves (wave = GN group), 4 tiles/block,
// double-buffered LDS staging. MFMA operands: A = z (row = pos), B = W
// (col = o)  ->  D[row=pos][col=o]: lane owns o = lane&15, reg-quad = 4
// consecutive positions (float4 stores in k3).
// ---------------------------------------------------------------------------
#define WFRAG_LOAD()                                                           \
  const int lr = tid & 15, lg = (tid >> 4) & 3, wv = tid >> 6;                 \
  const int obase = wv * 32;                                                   \
  short8v wfrag[2][2];                                                         \
  _Pragma("unroll")                                                            \
  for (int ot = 0; ot < 2; ++ot)                                               \
    _Pragma("unroll")                                                          \
    for (int kt = 0; kt < 2; ++kt) {                                           \
      int o  = obase + ot * 16 + lr;                                           \
      int c0 = kt * 32 + lg * 8;                                               \
      float4 wa = *(const float4*)(pw + o * 64 + c0);                          \
      float4 wb = *(const float4*)(pw + o * 64 + c0 + 4);                      \
      short8v fr;                                                              \
      fr[0] = (short)f2bf(wa.x); fr[1] = (short)f2bf(wa.y);                    \
      fr[2] = (short)f2bf(wa.z); fr[3] = (short)f2bf(wa.w);                    \
      fr[4] = (short)f2bf(wb.x); fr[5] = (short)f2bf(wb.y);                    \
      fr[6] = (short)f2bf(wb.z); fr[7] = (short)f2bf(wb.w);                    \
      wfrag[ot][kt] = fr;                                                      \
    }

#define LDR(it) {                                                              \
  int p0 = (it) * 128;                                                         \
  _Pragma("unroll")                                                            \
  for (int i = 0; i < 4; ++i) {                                                \
    int f = tid + i * 256; int c2r = f >> 5; int po = (f & 31) << 2;           \
    st[i] = *(const uint4*)(zb + (size_t)c2r * THW + p0 + po);                 \
  } }

#define STL(bf) {                                                              \
  _Pragma("unroll")                                                            \
  for (int i = 0; i < 4; ++i) {                                                \
    int f = tid + i * 256; int c2r = f >> 5; int po = (f & 31) << 2;           \
    *(uint4*)&zt[bf][c2r * 132 + po] = st[i];                                  \
  } }

#define MFMA_TILE(bufidx)                                                      \
  f32x4 acc[2][8];                                                             \
  _Pragma("unroll")                                                            \
  for (int ot = 0; ot < 2; ++ot)                                               \
    _Pragma("unroll")                                                          \
    for (int pt = 0; pt < 8; ++pt) {                                           \
      acc[ot][pt][0] = 0.f; acc[ot][pt][1] = 0.f;                              \
      acc[ot][pt][2] = 0.f; acc[ot][pt][3] = 0.f;                              \
    }                                                                          \
  {                                                                            \
    const unsigned int* ztc = zt[bufidx];                                      \
    _Pragma("unroll")                                                          \
    for (int kt = 0; kt < 2; ++kt) {                                           \
      const int c2b = kt * 16 + lg * 4;                                        \
      _Pragma("unroll")                                                        \
      for (int pt = 0; pt < 8; ++pt) {                                         \
        const unsigned int* zp2 = &ztc[c2b * 132 + pt * 16 + lr];              \
        union { unsigned int u[4]; short8v s; } zfu;                           \
        zfu.u[0] = zp2[0];   zfu.u[1] = zp2[132];                              \
        zfu.u[2] = zp2[264]; zfu.u[3] = zp2[396];                              \
        acc[0][pt] = __builtin_amdgcn_mfma_f32_16x16x32_bf16(                  \
            zfu.s, wfrag[0][kt], acc[0][pt], 0, 0, 0);                         \
        acc[1][pt] = __builtin_amdgcn_mfma_f32_16x16x32_bf16(                  \
            zfu.s, wfrag[1][kt], acc[1][pt], 0, 0, 0);                         \
      }                                                                        \
    }                                                                          \
  }

// K2: GEMM over 4 tiles -> per-(b,group) sum / sumsq (double atomics).
__global__ __launch_bounds__(256) void k2_stats(
    const unsigned int* __restrict__ zq, const float* __restrict__ pw,
    const float* __restrict__ pb, double* __restrict__ stats)
{
  __shared__ unsigned int zt[2][32 * 132];   // 33.8 KB
  const int tid = threadIdx.x;
  const int b  = blockIdx.x / 98;
  const int pg = blockIdx.x - b * 98;

  WFRAG_LOAD();

  const float pbl[2] = { pb[obase + lr], pb[obase + 16 + lr] };

  const unsigned int* zb = zq + (size_t)(b * 32) * THW + pg * 512;

  uint4 st[4];
  LDR(0); STL(0);

  float s1 = 0.0f, s2 = 0.0f;
  for (int it = 0; it < 4; ++it) {
    __syncthreads();
    if (it < 3) LDR(it + 1);
    MFMA_TILE(it & 1);
    if (it < 3) STL((it + 1) & 1);
#pragma unroll
    for (int ot = 0; ot < 2; ++ot)
#pragma unroll
      for (int pt = 0; pt < 8; ++pt)
#pragma unroll
        for (int r = 0; r < 4; ++r) {
          float d = acc[ot][pt][r] + pbl[ot];
          s1 += d;
          s2 = fmaf(d, d, s2);
        }
  }

#pragma unroll
  for (int off = 32; off; off >>= 1) {
    s1 += __shfl_xor(s1, off);
    s2 += __shfl_xor(s2, off);
  }
  if ((tid & 63) == 0) {
    atomicAdd(&stats[(b * 4 + wv) * 2 + 0], (double)s1);
    atomicAdd(&stats[(b * 4 + wv) * 2 + 1], (double)s2);
  }
}

// K3: GEMM recompute over 4 tiles -> GroupNorm + affine + ReLU -> out.
__global__ __launch_bounds__(256) void k3_norm(
    const unsigned int* __restrict__ zq, const float* __restrict__ pw,
    const float* __restrict__ pb, const double* __restrict__ stats,
    const float* __restrict__ gnw, const float* __restrict__ gnb,
    float* __restrict__ out)
{
  __shared__ unsigned int zt[2][32 * 132];
  const int tid = threadIdx.x;
  const int b  = blockIdx.x / 98;
  const int pg = blockIdx.x - b * 98;

  WFRAG_LOAD();

  double sm1 = stats[(b * 4 + wv) * 2 + 0];
  double sm2 = stats[(b * 4 + wv) * 2 + 1];
  double md = sm1 / NPG;
  double vd = sm2 / NPG - md * md;
  float m   = (float)md;
  float inv = rsqrtf((float)vd + 1e-5f);

  float Ac[2], Bc[2];
#pragma unroll
  for (int ot = 0; ot < 2; ++ot) {
    int o = obase + ot * 16 + lr;
    float A = inv * gnw[o];
    Ac[ot] = A;
    Bc[ot] = fmaf(pb[o] - m, A, gnb[o]);
  }

  const unsigned int* zb = zq + (size_t)(b * 32) * THW + pg * 512;
  float* ob = out + (size_t)(b * COUT) * THW + pg * 512 + lg * 4;

  uint4 st[4];
  LDR(0); STL(0);

  for (int it = 0; it < 4; ++it) {
    __syncthreads();
    if (it < 3) LDR(it + 1);
    MFMA_TILE(it & 1);
    if (it < 3) STL((it + 1) & 1);
#pragma unroll
    for (int ot = 0; ot < 2; ++ot) {
      int o = obase + ot * 16 + lr;
      float A = Ac[ot], B = Bc[ot];
      float* orow = ob + (size_t)o * THW + it * 128;
#pragma unroll
      for (int pt = 0; pt < 8; ++pt) {
        f32x4 a = acc[ot][pt];
        f32x4 v;
        v[0] = fmaf(a[0], A, B); v[0] = v[0] > 0.0f ? v[0] : 0.0f;
        v[1] = fmaf(a[1], A, B); v[1] = v[1] > 0.0f ? v[1] : 0.0f;
        v[2] = fmaf(a[2], A, B); v[2] = v[2] > 0.0f ? v[2] : 0.0f;
        v[3] = fmaf(a[3], A, B); v[3] = v[3] > 0.0f ? v[3] : 0.0f;
        __builtin_nontemporal_store(v, (f32x4*)(orow + pt * 16));
      }
    }
  }
}

// ---------------------------------------------------------------------------
extern "C" void kernel_launch(void* const* d_in, const int* in_sizes, int n_in,
                              void* d_out, int out_size, void* d_ws, size_t ws_size,
                              hipStream_t stream)
{
  const float* x   = (const float*)d_in[0];
  const float* sw  = (const float*)d_in[1];
  const float* sb  = (const float*)d_in[2];
  const float* tw  = (const float*)d_in[3];
  const float* tb  = (const float*)d_in[4];
  const float* pw  = (const float*)d_in[5];
  const float* pb  = (const float*)d_in[6];
  const float* gnw = (const float*)d_in[7];
  const float* gnb = (const float*)d_in[8];
  float* out = (float*)d_out;

  double* stats    = (double*)d_ws;                        // 64 doubles
  unsigned int* zq = (unsigned int*)((char*)d_ws + 512);   // bf16-pair z

  k1_dwconv<<<Bb * 32 * 4, 256, 0, stream>>>(x, sw, sb, tw, tb, zq, stats);
  k2_stats<<<Bb * 98, 256, 0, stream>>>(zq, pw, pb, stats);
  k3_norm <<<Bb * 98, 256, 0, stream>>>(zq, pw, pb, stats, gnw, gnb, out);
}

// Round 8
// 168.983 us; speedup vs baseline: 1.0813x; 1.0813x over previous
//
#include <hip/hip_runtime.h>
#include <hip/hip_bf16.h>

#define Bb 8
#define Cc 64
#define Tt 16
#define Hh 56
#define Ww 56
#define COUT 128
#define HW (Hh*Ww)            // 3136
#define THW (Tt*HW)           // 50176
#define NPG ((double)(32*THW))

typedef __attribute__((ext_vector_type(8))) short short8v;   // 8 bf16
typedef __attribute__((ext_vector_type(4))) float f32x4;

__device__ __forceinline__ unsigned short f2bf(float x) {
  __hip_bfloat16 h = __float2bfloat16(x);
  return *reinterpret_cast<unsigned short*>(&h);
}
__device__ __forceinline__ float blo(unsigned int u) {
  return __uint_as_float(u << 16);
}
__device__ __forceinline__ float bhi(unsigned int u) {
  return __uint_as_float(u & 0xFFFF0000u);
}
__device__ __forceinline__ unsigned int pack2(float a, float b) {
  return (unsigned int)f2bf(a) | ((unsigned int)f2bf(b) << 16);
}

// ---------------------------------------------------------------------------
// K1: fused depthwise spatial 3x3 + temporal 3-tap. One block per
// (b, channel-PAIR, t-quad). raw & ring planes live in LDS as packed bf16
// pairs. Block 0 also zeroes the stats buffer (runs before k2 in stream order).
// ---------------------------------------------------------------------------
__global__ __launch_bounds__(256) void k1_dwconv(
    const float* __restrict__ x,  const float* __restrict__ sw,
    const float* __restrict__ sb, const float* __restrict__ tw,
    const float* __restrict__ tb, unsigned int* __restrict__ zq,
    double* __restrict__ stats)
{
  __shared__ unsigned int raw[HW];        // 12.25 KB (bf16 pair)
  __shared__ unsigned int ring[3][HW];    // 36.75 KB

  const int tid = threadIdx.x;
  if (blockIdx.x == 0 && tid < 64) stats[tid] = 0.0;

  const int tq = blockIdx.x & 3;
  const int c2 = (blockIdx.x >> 2) & 31;
  const int b  =  blockIdx.x >> 7;
  const int t0 = tq * 4;
  const int ca = c2 * 2, cb = ca + 1;

  float s9a[9], s9b[9];
#pragma unroll
  for (int k = 0; k < 9; ++k) { s9a[k] = sw[ca * 9 + k]; s9b[k] = sw[cb * 9 + k]; }
  float ta3[3], tb3[3];
#pragma unroll
  for (int k = 0; k < 3; ++k) { ta3[k] = tw[ca * 3 + k]; tb3[k] = tw[cb * 3 + k]; }
  const float sba = sb[ca], sbb = sb[cb];
  const float tba = tb[ca], tbb = tb[cb];

  const float* xa = x + (size_t)(b * Cc + ca) * THW;
  const float* xb = x + (size_t)(b * Cc + cb) * THW;
  unsigned int* zbase = zq + (size_t)(b * 32 + c2) * THW;

  for (int tt = t0 - 1; tt <= t0 + 4; ++tt) {
    if (tt >= 0 && tt < Tt) {
      const float* xpa = xa + tt * HW;
      const float* xpb = xb + tt * HW;
      for (int f = tid; f < HW / 4; f += 256) {
        float4 va = *(const float4*)(xpa + f * 4);
        float4 vb = *(const float4*)(xpb + f * 4);
        uint4 pk;
        pk.x = pack2(va.x, vb.x);
        pk.y = pack2(va.y, vb.y);
        pk.z = pack2(va.z, vb.z);
        pk.w = pack2(va.w, vb.w);
        *(uint4*)&raw[f * 4] = pk;
      }
    }
    __syncthreads();

    if (tt >= 0 && tt < Tt) {
      unsigned int* rg = ring[tt % 3];
      for (int q = tid; q < HW / 4; q += 256) {
        int h  = q / 14;
        int w0 = (q - h * 14) * 4;
        float sa0 = sba, sa1 = sba, sa2 = sba, sa3 = sba;
        float sb0 = sbb, sb1 = sbb, sb2 = sbb, sb3 = sbb;
#pragma unroll
        for (int dh = -1; dh <= 1; ++dh) {
          int hh = h + dh;
          if (hh < 0 || hh > Hh - 1) continue;
          const unsigned int* rr = &raw[hh * Ww + w0];
          uint4 mv = *(const uint4*)rr;
          unsigned int lf = (w0 > 0)      ? rr[-1] : 0u;
          unsigned int rt = (w0 < Ww - 4) ? rr[4]  : 0u;
          float am1 = blo(lf),  a0 = blo(mv.x), a1 = blo(mv.y);
          float a2  = blo(mv.z), a3 = blo(mv.w), a4 = blo(rt);
          float bm1 = bhi(lf),  b0 = bhi(mv.x), b1 = bhi(mv.y);
          float b2  = bhi(mv.z), b3 = bhi(mv.w), b4 = bhi(rt);
          float k0a = s9a[(dh + 1) * 3 + 0], k1a = s9a[(dh + 1) * 3 + 1], k2a = s9a[(dh + 1) * 3 + 2];
          float k0b = s9b[(dh + 1) * 3 + 0], k1b = s9b[(dh + 1) * 3 + 1], k2b = s9b[(dh + 1) * 3 + 2];
          sa0 = fmaf(k0a, am1, fmaf(k1a, a0, fmaf(k2a, a1, sa0)));
          sa1 = fmaf(k0a, a0,  fmaf(k1a, a1, fmaf(k2a, a2, sa1)));
          sa2 = fmaf(k0a, a1,  fmaf(k1a, a2, fmaf(k2a, a3, sa2)));
          sa3 = fmaf(k0a, a2,  fmaf(k1a, a3, fmaf(k2a, a4, sa3)));
          sb0 = fmaf(k0b, bm1, fmaf(k1b, b0, fmaf(k2b, b1, sb0)));
          sb1 = fmaf(k0b, b0,  fmaf(k1b, b1, fmaf(k2b, b2, sb1)));
          sb2 = fmaf(k0b, b1,  fmaf(k1b, b2, fmaf(k2b, b3, sb2)));
          sb3 = fmaf(k0b, b2,  fmaf(k1b, b3, fmaf(k2b, b4, sb3)));
        }
        uint4 pk;
        pk.x = pack2(sa0, sb0);
        pk.y = pack2(sa1, sb1);
        pk.z = pack2(sa2, sb2);
        pk.w = pack2(sa3, sb3);
        *(uint4*)&rg[q * 4] = pk;
      }
    }
    __syncthreads();

    int t_out = tt - 1;
    if (t_out >= t0 && t_out <= t0 + 3) {
      unsigned int* zp = zbase + (size_t)t_out * HW;
      for (int q = tid; q < HW / 4; q += 256) {
        float aa0 = tba, aa1 = tba, aa2 = tba, aa3 = tba;
        float bb0 = tbb, bb1 = tbb, bb2 = tbb, bb3 = tbb;
#pragma unroll
        for (int dt = -1; dt <= 1; ++dt) {
          int ti = t_out + dt;
          if (ti < 0 || ti > Tt - 1) continue;
          float tka = ta3[dt + 1], tkb = tb3[dt + 1];
          uint4 v = *(const uint4*)&ring[ti % 3][q * 4];
          aa0 = fmaf(tka, blo(v.x), aa0);  bb0 = fmaf(tkb, bhi(v.x), bb0);
          aa1 = fmaf(tka, blo(v.y), aa1);  bb1 = fmaf(tkb, bhi(v.y), bb1);
          aa2 = fmaf(tka, blo(v.z), aa2);  bb2 = fmaf(tkb, bhi(v.z), bb2);
          aa3 = fmaf(tka, blo(v.w), aa3);  bb3 = fmaf(tkb, bhi(v.w), bb3);
        }
        uint4 o;
        o.x = pack2(aa0, bb0);
        o.y = pack2(aa1, bb1);
        o.z = pack2(aa2, bb2);
        o.w = pack2(aa3, bb3);
        *(uint4*)(zp + q * 4) = o;
      }
    }
    __syncthreads();
  }
}

// ---------------------------------------------------------------------------
// K2/K3: 128 pos x 128 out tile, 4 waves (wave = GN group), 4 tiles/block,
// double-buffered LDS staging. MFMA operands: A = z (row = pos), B = W
// (col = o)  ->  D[row=pos][col=o]: lane owns o = lane&15, reg-quad = 4
// consecutive positions (float4 stores in k3).
// ---------------------------------------------------------------------------
#define WFRAG_LOAD()                                                           \
  const int lr = tid & 15, lg = (tid >> 4) & 3, wv = tid >> 6;                 \
  const int obase = wv * 32;                                                   \
  short8v wfrag[2][2];                                                         \
  _Pragma("unroll")                                                            \
  for (int ot = 0; ot < 2; ++ot)                                               \
    _Pragma("unroll")                                                          \
    for (int kt = 0; kt < 2; ++kt) {                                           \
      int o  = obase + ot * 16 + lr;                                           \
      int c0 = kt * 32 + lg * 8;                                               \
      float4 wa = *(const float4*)(pw + o * 64 + c0);                          \
      float4 wb = *(const float4*)(pw + o * 64 + c0 + 4);                      \
      short8v fr;                                                              \
      fr[0] = (short)f2bf(wa.x); fr[1] = (short)f2bf(wa.y);                    \
      fr[2] = (short)f2bf(wa.z); fr[3] = (short)f2bf(wa.w);                    \
      fr[4] = (short)f2bf(wb.x); fr[5] = (short)f2bf(wb.y);                    \
      fr[6] = (short)f2bf(wb.z); fr[7] = (short)f2bf(wb.w);                    \
      wfrag[ot][kt] = fr;                                                      \
    }

#define LDR(it) {                                                              \
  int p0 = (it) * 128;                                                         \
  _Pragma("unroll")                                                            \
  for (int i = 0; i < 4; ++i) {                                                \
    int f = tid + i * 256; int c2r = f >> 5; int po = (f & 31) << 2;           \
    st[i] = *(const uint4*)(zb + (size_t)c2r * THW + p0 + po);                 \
  } }

#define STL(bf) {                                                              \
  _Pragma("unroll")                                                            \
  for (int i = 0; i < 4; ++i) {                                                \
    int f = tid + i * 256; int c2r = f >> 5; int po = (f & 31) << 2;           \
    *(uint4*)&zt[bf][c2r * 132 + po] = st[i];                                  \
  } }

#define MFMA_TILE(bufidx)                                                      \
  f32x4 acc[2][8];                                                             \
  _Pragma("unroll")                                                            \
  for (int ot = 0; ot < 2; ++ot)                                               \
    _Pragma("unroll")                                                          \
    for (int pt = 0; pt < 8; ++pt) {                                           \
      acc[ot][pt][0] = 0.f; acc[ot][pt][1] = 0.f;                              \
      acc[ot][pt][2] = 0.f; acc[ot][pt][3] = 0.f;                              \
    }                                                                          \
  {                                                                            \
    const unsigned int* ztc = zt[bufidx];                                      \
    _Pragma("unroll")                                                          \
    for (int kt = 0; kt < 2; ++kt) {                                           \
      const int c2b = kt * 16 + lg * 4;                                        \
      _Pragma("unroll")                                                        \
      for (int pt = 0; pt < 8; ++pt) {                                         \
        const unsigned int* zp2 = &ztc[c2b * 132 + pt * 16 + lr];              \
        union { unsigned int u[4]; short8v s; } zfu;                           \
        zfu.u[0] = zp2[0];   zfu.u[1] = zp2[132];                              \
        zfu.u[2] = zp2[264]; zfu.u[3] = zp2[396];                              \
        acc[0][pt] = __builtin_amdgcn_mfma_f32_16x16x32_bf16(                  \
            zfu.s, wfrag[0][kt], acc[0][pt], 0, 0, 0);                         \
        acc[1][pt] = __builtin_amdgcn_mfma_f32_16x16x32_bf16(                  \
            zfu.s, wfrag[1][kt], acc[1][pt], 0, 0, 0);                         \
      }                                                                        \
    }                                                                          \
  }

// K2: GEMM over 4 tiles -> per-(b,group) sum / sumsq (double atomics).
__global__ __launch_bounds__(256) void k2_stats(
    const unsigned int* __restrict__ zq, const float* __restrict__ pw,
    const float* __restrict__ pb, double* __restrict__ stats)
{
  __shared__ unsigned int zt[2][32 * 132];   // 33.8 KB
  const int tid = threadIdx.x;
  const int b  = blockIdx.x / 98;
  const int pg = blockIdx.x - b * 98;

  WFRAG_LOAD();

  const float pbl[2] = { pb[obase + lr], pb[obase + 16 + lr] };

  const unsigned int* zb = zq + (size_t)(b * 32) * THW + pg * 512;

  uint4 st[4];
  LDR(0); STL(0);

  float s1 = 0.0f, s2 = 0.0f;
  for (int it = 0; it < 4; ++it) {
    __syncthreads();
    if (it < 3) LDR(it + 1);
    MFMA_TILE(it & 1);
    if (it < 3) STL((it + 1) & 1);
#pragma unroll
    for (int ot = 0; ot < 2; ++ot)
#pragma unroll
      for (int pt = 0; pt < 8; ++pt)
#pragma unroll
        for (int r = 0; r < 4; ++r) {
          float d = acc[ot][pt][r] + pbl[ot];
          s1 += d;
          s2 = fmaf(d, d, s2);
        }
  }

#pragma unroll
  for (int off = 32; off; off >>= 1) {
    s1 += __shfl_xor(s1, off);
    s2 += __shfl_xor(s2, off);
  }
  if ((tid & 63) == 0) {
    atomicAdd(&stats[(b * 4 + wv) * 2 + 0], (double)s1);
    atomicAdd(&stats[(b * 4 + wv) * 2 + 1], (double)s2);
  }
}

// K3: GEMM recompute over 4 tiles -> GroupNorm + affine + ReLU -> out.
__global__ __launch_bounds__(256) void k3_norm(
    const unsigned int* __restrict__ zq, const float* __restrict__ pw,
    const float* __restrict__ pb, const double* __restrict__ stats,
    const float* __restrict__ gnw, const float* __restrict__ gnb,
    float* __restrict__ out)
{
  __shared__ unsigned int zt[2][32 * 132];
  const int tid = threadIdx.x;
  const int b  = blockIdx.x / 98;
  const int pg = blockIdx.x - b * 98;

  WFRAG_LOAD();

  double sm1 = stats[(b * 4 + wv) * 2 + 0];
  double sm2 = stats[(b * 4 + wv) * 2 + 1];
  double md = sm1 / NPG;
  double vd = sm2 / NPG - md * md;
  float m   = (float)md;
  float inv = rsqrtf((float)vd + 1e-5f);

  float Ac[2], Bc[2];
#pragma unroll
  for (int ot = 0; ot < 2; ++ot) {
    int o = obase + ot * 16 + lr;
    float A = inv * gnw[o];
    Ac[ot] = A;
    Bc[ot] = fmaf(pb[o] - m, A, gnb[o]);
  }

  const unsigned int* zb = zq + (size_t)(b * 32) * THW + pg * 512;
  float* ob = out + (size_t)(b * COUT) * THW + pg * 512 + lg * 4;

  uint4 st[4];
  LDR(0); STL(0);

  for (int it = 0; it < 4; ++it) {
    __syncthreads();
    if (it < 3) LDR(it + 1);
    MFMA_TILE(it & 1);
    if (it < 3) STL((it + 1) & 1);
#pragma unroll
    for (int ot = 0; ot < 2; ++ot) {
      int o = obase + ot * 16 + lr;
      float A = Ac[ot], B = Bc[ot];
      float* orow = ob + (size_t)o * THW + it * 128;
#pragma unroll
      for (int pt = 0; pt < 8; ++pt) {
        f32x4 a = acc[ot][pt];
        float4 v;
        v.x = fmaf(a[0], A, B); v.x = v.x > 0.0f ? v.x : 0.0f;
        v.y = fmaf(a[1], A, B); v.y = v.y > 0.0f ? v.y : 0.0f;
        v.z = fmaf(a[2], A, B); v.z = v.z > 0.0f ? v.z : 0.0f;
        v.w = fmaf(a[3], A, B); v.w = v.w > 0.0f ? v.w : 0.0f;
        *(float4*)(orow + pt * 16) = v;
      }
    }
  }
}

// ---------------------------------------------------------------------------
extern "C" void kernel_launch(void* const* d_in, const int* in_sizes, int n_in,
                              void* d_out, int out_size, void* d_ws, size_t ws_size,
                              hipStream_t stream)
{
  const float* x   = (const float*)d_in[0];
  const float* sw  = (const float*)d_in[1];
  const float* sb  = (const float*)d_in[2];
  const float* tw  = (const float*)d_in[3];
  const float* tb  = (const float*)d_in[4];
  const float* pw  = (const float*)d_in[5];
  const float* pb  = (const float*)d_in[6];
  const float* gnw = (const float*)d_in[7];
  const float* gnb = (const float*)d_in[8];
  float* out = (float*)d_out;

  double* stats    = (double*)d_ws;                        // 64 doubles
  unsigned int* zq = (unsigned int*)((char*)d_ws + 512);   // bf16-pair z

  k1_dwconv<<<Bb * 32 * 4, 256, 0, stream>>>(x, sw, sb, tw, tb, zq, stats);
  k2_stats<<<Bb * 98, 256, 0, stream>>>(zq, pw, pb, stats);
  k3_norm <<<Bb * 98, 256, 0, stream>>>(zq, pw, pb, stats, gnw, gnb, out);
}